// Round 1
// baseline (785.975 us; speedup 1.0000x reference)
//
#include <hip/hip_runtime.h>
#include <cstdint>
#include <cstddef>

// ---------------------------------------------------------------------------
// GIN forward: 3 x [gather(segment_sum) -> GEMM1+bias -> BN(train)+ReLU -> GEMM2+bias]
// CSR built once per call (histogram -> scan -> fill), reused by all 3 layers.
// ---------------------------------------------------------------------------

static constexpr float BN_EPS_F = 1e-5f;

// ------------------------- CSR build kernels -------------------------------

__global__ __launch_bounds__(256) void hist_kernel(const int* __restrict__ dst,
                                                   int* __restrict__ deg, int E) {
    int e = blockIdx.x * 256 + threadIdx.x;
    if (e < E) atomicAdd(&deg[dst[e]], 1);
}

__global__ __launch_bounds__(1024) void scan_part_kernel(const int* __restrict__ deg,
                                                         int* __restrict__ ex,
                                                         int* __restrict__ bsum, int n) {
    __shared__ int sm[1024];
    int t = threadIdx.x;
    int g = blockIdx.x * 1024 + t;
    int v = (g < n) ? deg[g] : 0;
    sm[t] = v;
    __syncthreads();
    #pragma unroll
    for (int off = 1; off < 1024; off <<= 1) {
        int x = (t >= off) ? sm[t - off] : 0;
        __syncthreads();
        sm[t] += x;
        __syncthreads();
    }
    int incl = sm[t];
    if (g < n) ex[g] = incl - v;            // exclusive within chunk
    if (t == 1023) bsum[blockIdx.x] = incl; // chunk total
}

__global__ __launch_bounds__(128) void scan_tops_kernel(int* __restrict__ bsum, int nb) {
    __shared__ int sm[128];
    int t = threadIdx.x;
    int v = (t < nb) ? bsum[t] : 0;
    sm[t] = v;
    __syncthreads();
    #pragma unroll
    for (int off = 1; off < 128; off <<= 1) {
        int x = (t >= off) ? sm[t - off] : 0;
        __syncthreads();
        sm[t] += x;
        __syncthreads();
    }
    if (t < nb) bsum[t] = sm[t] - v;        // exclusive totals
}

__global__ __launch_bounds__(1024) void scan_add_kernel(int* __restrict__ starts,
                                                        const int* __restrict__ bsum,
                                                        int n, int E) {
    int g = blockIdx.x * 1024 + threadIdx.x;
    if (g < n) starts[g] += bsum[blockIdx.x];
    if (g == 0) starts[n] = E;
}

__global__ __launch_bounds__(256) void fill_kernel(const int* __restrict__ src,
                                                   const int* __restrict__ dst,
                                                   int* __restrict__ cursor,
                                                   int* __restrict__ srcs, int E) {
    int e = blockIdx.x * 256 + threadIdx.x;
    if (e < E) {
        int d = dst[e];
        int p = atomicAdd(&cursor[d], 1);
        srcs[p] = src[e];
    }
}

// ------------------------- gather: pre = x + segment_sum(x[src]) -----------

template <int D>
__global__ __launch_bounds__(64) void gather_kernel(const float* __restrict__ x,
                                                    const int* __restrict__ starts,
                                                    const int* __restrict__ srcs,
                                                    float* __restrict__ pre, int n) {
    int node = blockIdx.x;
    int lane = threadIdx.x;
    int s = starts[node];
    int e = starts[node + 1];
    float a0 = x[(size_t)node * D + lane];
    float a1 = (D == 128) ? x[(size_t)node * D + 64 + lane] : 0.f;
    for (int j = s; j < e; ++j) {
        int sn = srcs[j];
        const float* row = x + (size_t)sn * D;
        a0 += row[lane];
        if (D == 128) a1 += row[64 + lane];
    }
    pre[(size_t)node * D + lane] = a0;
    if (D == 128) pre[(size_t)node * D + 64 + lane] = a1;
}

// ------------------------- GEMM: C = act(A) @ W + bias ---------------------
// act(A) = BN ? relu(A*scale + shift) : A  (elementwise per input column)
// Block: 64 rows x DO cols, 256 threads, 4x(DO/16) micro-tile per thread.

template <int DI, int DO, bool BN>
__global__ __launch_bounds__(256) void gemm_kernel(const float* __restrict__ A,
                                                   const float* __restrict__ W,
                                                   const float* __restrict__ bias,
                                                   const float* __restrict__ scale,
                                                   const float* __restrict__ shift,
                                                   float* __restrict__ C, int nrows) {
    constexpr int LDA = DI + 4;     // pad: rows 4 apart land on distinct bank quads
    constexpr int CPT = DO / 16;    // cols per thread (8 or 4)
    extern __shared__ float lds[];
    float* As = lds;                // 64 x LDA
    float* Ws = lds + 64 * LDA;     // DI x DO

    const int t = threadIdx.x;
    const int r0 = blockIdx.x * 64;

    // ---- stage A tile (with optional BN+ReLU) ----
    constexpr int F4_ROW = DI / 4;
    #pragma unroll
    for (int i = 0; i < 64 * F4_ROW / 256; ++i) {
        int f = t + i * 256;
        int row = f / F4_ROW;
        int c4 = (f % F4_ROW) * 4;
        float4 v = make_float4(0.f, 0.f, 0.f, 0.f);
        int gr = r0 + row;
        if (gr < nrows) {
            v = *reinterpret_cast<const float4*>(A + (size_t)gr * DI + c4);
            if (BN) {
                float4 sc = *reinterpret_cast<const float4*>(scale + c4);
                float4 sh = *reinterpret_cast<const float4*>(shift + c4);
                v.x = fmaxf(fmaf(v.x, sc.x, sh.x), 0.f);
                v.y = fmaxf(fmaf(v.y, sc.y, sh.y), 0.f);
                v.z = fmaxf(fmaf(v.z, sc.z, sh.z), 0.f);
                v.w = fmaxf(fmaf(v.w, sc.w, sh.w), 0.f);
            }
        }
        *reinterpret_cast<float4*>(As + row * LDA + c4) = v;
    }
    // ---- stage W ----
    #pragma unroll
    for (int i = 0; i < DI * DO / 4 / 256; ++i) {
        int f = t + i * 256;
        int k = f / (DO / 4);
        int c4 = (f % (DO / 4)) * 4;
        *reinterpret_cast<float4*>(Ws + k * DO + c4) =
            *reinterpret_cast<const float4*>(W + (size_t)k * DO + c4);
    }
    __syncthreads();

    const int rg = t >> 4;
    const int cg = t & 15;
    const int rowb = rg * 4;
    const int colb = cg * CPT;

    float acc[4][CPT];
    #pragma unroll
    for (int r = 0; r < 4; ++r)
        #pragma unroll
        for (int c = 0; c < CPT; ++c) acc[r][c] = 0.f;

    #pragma unroll 2
    for (int k0 = 0; k0 < DI; k0 += 4) {
        float4 a[4];
        #pragma unroll
        for (int r = 0; r < 4; ++r)
            a[r] = *reinterpret_cast<const float4*>(As + (rowb + r) * LDA + k0);
        #pragma unroll
        for (int kk = 0; kk < 4; ++kk) {
            #pragma unroll
            for (int j4 = 0; j4 < CPT / 4; ++j4) {
                float4 wv = *reinterpret_cast<const float4*>(Ws + (k0 + kk) * DO + colb + j4 * 4);
                #pragma unroll
                for (int r = 0; r < 4; ++r) {
                    const float av = reinterpret_cast<const float*>(&a[r])[kk];
                    acc[r][j4 * 4 + 0] = fmaf(av, wv.x, acc[r][j4 * 4 + 0]);
                    acc[r][j4 * 4 + 1] = fmaf(av, wv.y, acc[r][j4 * 4 + 1]);
                    acc[r][j4 * 4 + 2] = fmaf(av, wv.z, acc[r][j4 * 4 + 2]);
                    acc[r][j4 * 4 + 3] = fmaf(av, wv.w, acc[r][j4 * 4 + 3]);
                }
            }
        }
    }

    // ---- epilogue: add bias, store ----
    #pragma unroll
    for (int r = 0; r < 4; ++r) {
        int gr = r0 + rowb + r;
        if (gr >= nrows) continue;
        #pragma unroll
        for (int j4 = 0; j4 < CPT / 4; ++j4) {
            float4 b = *reinterpret_cast<const float4*>(bias + colb + j4 * 4);
            float4 o;
            o.x = acc[r][j4 * 4 + 0] + b.x;
            o.y = acc[r][j4 * 4 + 1] + b.y;
            o.z = acc[r][j4 * 4 + 2] + b.z;
            o.w = acc[r][j4 * 4 + 3] + b.w;
            *reinterpret_cast<float4*>(C + (size_t)gr * DO + colb + j4 * 4) = o;
        }
    }
}

// ------------------------- BN stats: column sum & sumsq --------------------

template <int DO>
__global__ __launch_bounds__(256) void stats_kernel(const float* __restrict__ H,
                                                    float* __restrict__ sums, int nrows) {
    constexpr int G = 256 / DO;
    int t = threadIdx.x;
    int col = t % DO;
    int grp = t / DO;
    float s = 0.f, s2 = 0.f;
    for (int r = blockIdx.x * G + grp; r < nrows; r += gridDim.x * G) {
        float v = H[(size_t)r * DO + col];
        s += v;
        s2 = fmaf(v, v, s2);
    }
    __shared__ float sm[256], sm2[256];
    sm[t] = s;
    sm2[t] = s2;
    __syncthreads();
    if (grp == 0) {
        #pragma unroll
        for (int g = 1; g < G; ++g) {
            s += sm[g * DO + col];
            s2 += sm2[g * DO + col];
        }
        atomicAdd(&sums[col], s);
        atomicAdd(&sums[DO + col], s2);
    }
}

template <int DO>
__global__ void bn_finalize_kernel(const float* __restrict__ sums,
                                   const float* __restrict__ g,
                                   const float* __restrict__ be,
                                   float* __restrict__ scsh, int nrows) {
    int c = threadIdx.x;
    if (c < DO) {
        float inv_n = 1.0f / (float)nrows;
        float mu = sums[c] * inv_n;
        float var = sums[DO + c] * inv_n - mu * mu;
        float inv = rsqrtf(var + BN_EPS_F);
        float sc = g[c] * inv;
        scsh[c] = sc;
        scsh[DO + c] = fmaf(-mu, sc, be[c]);
    }
}

// ------------------------- host orchestration ------------------------------

static inline size_t align_up(size_t v, size_t a) { return (v + a - 1) & ~(a - 1); }

extern "C" void kernel_launch(void* const* d_in, const int* in_sizes, int n_in,
                              void* d_out, int out_size, void* d_ws, size_t ws_size,
                              hipStream_t stream) {
    const float* x = (const float*)d_in[0];
    const int* ei = (const int*)d_in[1];
    const int N = in_sizes[0] / 64;
    const int E = in_sizes[1] / 2;
    const int* src = ei;
    const int* dst = ei + E;

    // per-layer params: 2 + 6*l + {w1,b1,g,be,w2,b2}
    const float* w1[3]; const float* b1[3]; const float* gg[3];
    const float* be[3]; const float* w2[3]; const float* b2[3];
    for (int l = 0; l < 3; ++l) {
        w1[l] = (const float*)d_in[2 + 6 * l + 0];
        b1[l] = (const float*)d_in[2 + 6 * l + 1];
        gg[l] = (const float*)d_in[2 + 6 * l + 2];
        be[l] = (const float*)d_in[2 + 6 * l + 3];
        w2[l] = (const float*)d_in[2 + 6 * l + 4];
        b2[l] = (const float*)d_in[2 + 6 * l + 5];
    }

    // ---- workspace suballocation (64B aligned) ----
    char* ws = (char*)d_ws;
    size_t off = 0;
    auto alloc = [&](size_t bytes) {
        void* p = ws + off;
        off = align_up(off + bytes, 64);
        return p;
    };
    float* B0   = (float*)alloc((size_t)N * 128 * 4);
    float* B1   = (float*)alloc((size_t)N * 128 * 4);
    int* srcs   = (int*)alloc((size_t)E * 4);
    int* starts = (int*)alloc((size_t)(N + 1) * 4);
    int* cursor = (int*)alloc((size_t)N * 4);
    int* bsum   = (int*)alloc(256 * 4);
    float* sums = (float*)alloc(256 * 4);
    float* scsh = (float*)alloc(256 * 4);
    (void)ws_size; (void)n_in; (void)out_size;

    // ---- raise LDS limits for big-tile GEMMs ----
    auto smem_sz = [](int DI, int DO) { return (size_t)(64 * (DI + 4) + DI * DO) * 4; };
    hipFuncSetAttribute((const void*)&gemm_kernel<128, 128, false>,
                        hipFuncAttributeMaxDynamicSharedMemorySize, (int)smem_sz(128, 128));
    hipFuncSetAttribute((const void*)&gemm_kernel<128, 128, true>,
                        hipFuncAttributeMaxDynamicSharedMemorySize, (int)smem_sz(128, 128));
    hipFuncSetAttribute((const void*)&gemm_kernel<128, 64, false>,
                        hipFuncAttributeMaxDynamicSharedMemorySize, (int)smem_sz(128, 64));

    // ---- CSR build (once, reused by all 3 layers) ----
    hipMemsetAsync(cursor, 0, (size_t)N * 4, stream);  // cursor doubles as deg
    hist_kernel<<<(E + 255) / 256, 256, 0, stream>>>(dst, cursor, E);
    int chunks = (N + 1023) / 1024;
    scan_part_kernel<<<chunks, 1024, 0, stream>>>(cursor, starts, bsum, N);
    scan_tops_kernel<<<1, 128, 0, stream>>>(bsum, chunks);
    scan_add_kernel<<<chunks, 1024, 0, stream>>>(starts, bsum, N, E);
    hipMemcpyAsync(cursor, starts, (size_t)N * 4, hipMemcpyDeviceToDevice, stream);
    fill_kernel<<<(E + 255) / 256, 256, 0, stream>>>(src, dst, cursor, srcs, E);

    const int nb = (N + 63) / 64;

    // ---- layer 0: 64 -> 128 -> 128 ----
    gather_kernel<64><<<N, 64, 0, stream>>>(x, starts, srcs, B0, N);
    gemm_kernel<64, 128, false><<<nb, 256, smem_sz(64, 128), stream>>>(
        B0, w1[0], b1[0], nullptr, nullptr, B1, N);
    hipMemsetAsync(sums, 0, 2 * 128 * 4, stream);
    stats_kernel<128><<<512, 256, 0, stream>>>(B1, sums, N);
    bn_finalize_kernel<128><<<1, 128, 0, stream>>>(sums, gg[0], be[0], scsh, N);
    gemm_kernel<128, 128, true><<<nb, 256, smem_sz(128, 128), stream>>>(
        B1, w2[0], b2[0], scsh, scsh + 128, B0, N);

    // ---- layer 1: 128 -> 128 -> 128 ----
    gather_kernel<128><<<N, 64, 0, stream>>>(B0, starts, srcs, B1, N);
    gemm_kernel<128, 128, false><<<nb, 256, smem_sz(128, 128), stream>>>(
        B1, w1[1], b1[1], nullptr, nullptr, B0, N);
    hipMemsetAsync(sums, 0, 2 * 128 * 4, stream);
    stats_kernel<128><<<512, 256, 0, stream>>>(B0, sums, N);
    bn_finalize_kernel<128><<<1, 128, 0, stream>>>(sums, gg[1], be[1], scsh, N);
    gemm_kernel<128, 128, true><<<nb, 256, smem_sz(128, 128), stream>>>(
        B0, w2[1], b2[1], scsh, scsh + 128, B1, N);

    // ---- layer 2: 128 -> 64 -> 64 ----
    gather_kernel<128><<<N, 64, 0, stream>>>(B1, starts, srcs, B0, N);
    gemm_kernel<128, 64, false><<<nb, 256, smem_sz(128, 64), stream>>>(
        B0, w1[2], b1[2], nullptr, nullptr, B1, N);
    hipMemsetAsync(sums, 0, 2 * 64 * 4, stream);
    stats_kernel<64><<<512, 256, 0, stream>>>(B1, sums, N);
    bn_finalize_kernel<64><<<1, 64, 0, stream>>>(sums, gg[2], be[2], scsh, N);
    gemm_kernel<64, 64, true><<<nb, 256, smem_sz(64, 64), stream>>>(
        B1, w2[2], b2[2], scsh, scsh + 64, (float*)d_out, N);
}

// Round 2
// 718.193 us; speedup vs baseline: 1.0944x; 1.0944x over previous
//
#include <hip/hip_runtime.h>
#include <cstdint>
#include <cstddef>

// ---------------------------------------------------------------------------
// GIN forward: 3 x [gather(segment_sum) -> GEMM1+bias -> BN(train)+ReLU -> GEMM2+bias]
// CSR built once per call; GEMMs use split-bf16 MFMA (a_hi+a_lo, 3 products)
// with weights pre-split/transposed to bf16 hi/lo planes once per call.
// ---------------------------------------------------------------------------

static constexpr float BN_EPS_F = 1e-5f;

typedef __attribute__((ext_vector_type(8))) short bf16x8;
typedef __attribute__((ext_vector_type(4))) float f32x4;

__device__ __forceinline__ short bf16_rne(float f) {
    uint32_t u = __builtin_bit_cast(uint32_t, f);
    u += 0x7fffu + ((u >> 16) & 1u);
    return (short)(u >> 16);
}
__device__ __forceinline__ float bf16_f(short s) {
    uint32_t u = ((uint32_t)(uint16_t)s) << 16;
    return __builtin_bit_cast(float, u);
}

// ------------------------- CSR build kernels -------------------------------

__global__ __launch_bounds__(256) void hist_kernel(const int* __restrict__ dst,
                                                   int* __restrict__ deg, int E) {
    int e = blockIdx.x * 256 + threadIdx.x;
    if (e < E) atomicAdd(&deg[dst[e]], 1);
}

__global__ __launch_bounds__(1024) void scan_part_kernel(const int* __restrict__ deg,
                                                         int* __restrict__ ex,
                                                         int* __restrict__ bsum, int n) {
    __shared__ int sm[1024];
    int t = threadIdx.x;
    int g = blockIdx.x * 1024 + t;
    int v = (g < n) ? deg[g] : 0;
    sm[t] = v;
    __syncthreads();
    #pragma unroll
    for (int off = 1; off < 1024; off <<= 1) {
        int x = (t >= off) ? sm[t - off] : 0;
        __syncthreads();
        sm[t] += x;
        __syncthreads();
    }
    int incl = sm[t];
    if (g < n) ex[g] = incl - v;
    if (t == 1023) bsum[blockIdx.x] = incl;
}

__global__ __launch_bounds__(128) void scan_tops_kernel(int* __restrict__ bsum, int nb) {
    __shared__ int sm[128];
    int t = threadIdx.x;
    int v = (t < nb) ? bsum[t] : 0;
    sm[t] = v;
    __syncthreads();
    #pragma unroll
    for (int off = 1; off < 128; off <<= 1) {
        int x = (t >= off) ? sm[t - off] : 0;
        __syncthreads();
        sm[t] += x;
        __syncthreads();
    }
    if (t < nb) bsum[t] = sm[t] - v;
}

__global__ __launch_bounds__(1024) void scan_add_kernel(int* __restrict__ starts,
                                                        const int* __restrict__ bsum,
                                                        int n, int E) {
    int g = blockIdx.x * 1024 + threadIdx.x;
    if (g < n) starts[g] += bsum[blockIdx.x];
    if (g == 0) starts[n] = E;
}

__global__ __launch_bounds__(256) void fill_kernel(const int* __restrict__ src,
                                                   const int* __restrict__ dst,
                                                   int* __restrict__ cursor,
                                                   int* __restrict__ srcs, int E) {
    int e = blockIdx.x * 256 + threadIdx.x;
    if (e < E) {
        int d = dst[e];
        int p = atomicAdd(&cursor[d], 1);
        srcs[p] = src[e];
    }
}

// ------------------------- gather: pre = x + segment_sum(x[src]) -----------

template <int D>
__global__ __launch_bounds__(64) void gather_kernel(const float* __restrict__ x,
                                                    const int* __restrict__ starts,
                                                    const int* __restrict__ srcs,
                                                    float* __restrict__ pre, int n) {
    int node = blockIdx.x;
    int lane = threadIdx.x;
    int s = starts[node];
    int e = starts[node + 1];
    float a0 = x[(size_t)node * D + lane];
    float a1 = (D == 128) ? x[(size_t)node * D + 64 + lane] : 0.f;
    for (int j = s; j < e; ++j) {
        int sn = srcs[j];
        const float* row = x + (size_t)sn * D;
        a0 += row[lane];
        if (D == 128) a1 += row[64 + lane];
    }
    pre[(size_t)node * D + lane] = a0;
    if (D == 128) pre[(size_t)node * D + 64 + lane] = a1;
}

// ------------------------- weight split: Wt_hi/lo[n][k] = split(W[k][n]) ---

__global__ __launch_bounds__(256) void wsplit_kernel(const float* __restrict__ W,
                                                     short* __restrict__ hi,
                                                     short* __restrict__ lo,
                                                     int K, int N) {
    int idx = blockIdx.x * 256 + threadIdx.x;
    if (idx < K * N) {
        int n = idx / K;
        int k = idx - n * K;
        float f = W[(size_t)k * N + n];
        short h = bf16_rne(f);
        hi[idx] = h;
        lo[idx] = bf16_rne(f - bf16_f(h));
    }
}

// ------------------------- MFMA GEMM: C = act(A) @ W + bias ----------------
// act(A) = BN ? relu(A*scale + shift) : A  (per input column k)
// Block: 256 thr = 4 waves; wave computes 32 rows x DO cols; no LDS.
// A: fp32 global, split to bf16 hi/lo in-reg. W: pre-split bf16 [DO][DI].
// mfma_f32_16x16x32_bf16 layout: A lane: m=lane&15, k=(lane>>4)*8+j;
// B lane: n=lane&15, k=(lane>>4)*8+j; D: col=lane&15, row=(lane>>4)*4+reg.

template <int DI, int DO, bool BN>
__global__ __launch_bounds__(256) void gemm_mfma(const float* __restrict__ A,
                                                 const short* __restrict__ Wh,
                                                 const short* __restrict__ Wl,
                                                 const float* __restrict__ bias,
                                                 const float* __restrict__ scale,
                                                 const float* __restrict__ shift,
                                                 float* __restrict__ C, int nrows) {
    constexpr int NF = DO / 16;
    constexpr int KI = DI / 32;

    const int t = threadIdx.x;
    const int wave = t >> 6;
    const int lane = t & 63;
    const int lr = lane & 15;
    const int kb = lane >> 4;

    const int row_base = blockIdx.x * 128 + wave * 32;
    const int r0 = row_base + lr;
    const int r1 = r0 + 16;
    const float* a0p = A + (size_t)(r0 < nrows ? r0 : 0) * DI + kb * 8;
    const float* a1p = A + (size_t)(r1 < nrows ? r1 : 0) * DI + kb * 8;

    f32x4 acc[2][NF];
    #pragma unroll
    for (int m = 0; m < 2; ++m)
        #pragma unroll
        for (int nf = 0; nf < NF; ++nf) acc[m][nf] = f32x4{0.f, 0.f, 0.f, 0.f};

    #pragma unroll
    for (int ki = 0; ki < KI; ++ki) {
        const int k0 = ki * 32;
        f32x4 a0a = *reinterpret_cast<const f32x4*>(a0p + k0);
        f32x4 a0b = *reinterpret_cast<const f32x4*>(a0p + k0 + 4);
        f32x4 a1a = *reinterpret_cast<const f32x4*>(a1p + k0);
        f32x4 a1b = *reinterpret_cast<const f32x4*>(a1p + k0 + 4);
        if (BN) {
            const int kk = k0 + kb * 8;
            f32x4 sca = *reinterpret_cast<const f32x4*>(scale + kk);
            f32x4 scb = *reinterpret_cast<const f32x4*>(scale + kk + 4);
            f32x4 sha = *reinterpret_cast<const f32x4*>(shift + kk);
            f32x4 shb = *reinterpret_cast<const f32x4*>(shift + kk + 4);
            #pragma unroll
            for (int j = 0; j < 4; ++j) {
                a0a[j] = fmaxf(fmaf(a0a[j], sca[j], sha[j]), 0.f);
                a0b[j] = fmaxf(fmaf(a0b[j], scb[j], shb[j]), 0.f);
                a1a[j] = fmaxf(fmaf(a1a[j], sca[j], sha[j]), 0.f);
                a1b[j] = fmaxf(fmaf(a1b[j], scb[j], shb[j]), 0.f);
            }
        }
        // split fp32 -> bf16 hi/lo
        bf16x8 ah0, al0, ah1, al1;
        #pragma unroll
        for (int j = 0; j < 4; ++j) {
            short h;
            h = bf16_rne(a0a[j]); ah0[j] = h;     al0[j] = bf16_rne(a0a[j] - bf16_f(h));
            h = bf16_rne(a0b[j]); ah0[j + 4] = h; al0[j + 4] = bf16_rne(a0b[j] - bf16_f(h));
            h = bf16_rne(a1a[j]); ah1[j] = h;     al1[j] = bf16_rne(a1a[j] - bf16_f(h));
            h = bf16_rne(a1b[j]); ah1[j + 4] = h; al1[j + 4] = bf16_rne(a1b[j] - bf16_f(h));
        }
        #pragma unroll
        for (int nf = 0; nf < NF; ++nf) {
            const size_t woff = (size_t)(nf * 16 + lr) * DI + k0 + kb * 8;
            bf16x8 bh = *reinterpret_cast<const bf16x8*>(Wh + woff);
            bf16x8 bl = *reinterpret_cast<const bf16x8*>(Wl + woff);
            acc[0][nf] = __builtin_amdgcn_mfma_f32_16x16x32_bf16(ah0, bh, acc[0][nf], 0, 0, 0);
            acc[0][nf] = __builtin_amdgcn_mfma_f32_16x16x32_bf16(al0, bh, acc[0][nf], 0, 0, 0);
            acc[0][nf] = __builtin_amdgcn_mfma_f32_16x16x32_bf16(ah0, bl, acc[0][nf], 0, 0, 0);
            acc[1][nf] = __builtin_amdgcn_mfma_f32_16x16x32_bf16(ah1, bh, acc[1][nf], 0, 0, 0);
            acc[1][nf] = __builtin_amdgcn_mfma_f32_16x16x32_bf16(al1, bh, acc[1][nf], 0, 0, 0);
            acc[1][nf] = __builtin_amdgcn_mfma_f32_16x16x32_bf16(ah1, bl, acc[1][nf], 0, 0, 0);
        }
    }

    // epilogue: bias + store (row = base + mf*16 + kb*4 + reg, col = nf*16 + lr)
    #pragma unroll
    for (int mf = 0; mf < 2; ++mf) {
        const int rbase = row_base + mf * 16 + kb * 4;
        #pragma unroll
        for (int nf = 0; nf < NF; ++nf) {
            const int col = nf * 16 + lr;
            const float b = bias[col];
            #pragma unroll
            for (int reg = 0; reg < 4; ++reg) {
                const int r = rbase + reg;
                if (r < nrows) C[(size_t)r * DO + col] = acc[mf][nf][reg] + b;
            }
        }
    }
}

// ------------------------- BN stats: column sum & sumsq --------------------

template <int DO>
__global__ __launch_bounds__(256) void stats_kernel(const float* __restrict__ H,
                                                    float* __restrict__ sums, int nrows) {
    constexpr int G = 256 / DO;
    int t = threadIdx.x;
    int col = t % DO;
    int grp = t / DO;
    float s = 0.f, s2 = 0.f;
    for (int r = blockIdx.x * G + grp; r < nrows; r += gridDim.x * G) {
        float v = H[(size_t)r * DO + col];
        s += v;
        s2 = fmaf(v, v, s2);
    }
    __shared__ float sm[256], sm2[256];
    sm[t] = s;
    sm2[t] = s2;
    __syncthreads();
    if (grp == 0) {
        #pragma unroll
        for (int g = 1; g < G; ++g) {
            s += sm[g * DO + col];
            s2 += sm2[g * DO + col];
        }
        atomicAdd(&sums[col], s);
        atomicAdd(&sums[DO + col], s2);
    }
}

template <int DO>
__global__ void bn_finalize_kernel(const float* __restrict__ sums,
                                   const float* __restrict__ g,
                                   const float* __restrict__ be,
                                   float* __restrict__ scsh, int nrows) {
    int c = threadIdx.x;
    if (c < DO) {
        float inv_n = 1.0f / (float)nrows;
        float mu = sums[c] * inv_n;
        float var = sums[DO + c] * inv_n - mu * mu;
        float inv = rsqrtf(var + BN_EPS_F);
        float sc = g[c] * inv;
        scsh[c] = sc;
        scsh[DO + c] = fmaf(-mu, sc, be[c]);
    }
}

// ------------------------- host orchestration ------------------------------

static inline size_t align_up(size_t v, size_t a) { return (v + a - 1) & ~(a - 1); }

extern "C" void kernel_launch(void* const* d_in, const int* in_sizes, int n_in,
                              void* d_out, int out_size, void* d_ws, size_t ws_size,
                              hipStream_t stream) {
    const float* x = (const float*)d_in[0];
    const int* ei = (const int*)d_in[1];
    const int N = in_sizes[0] / 64;
    const int E = in_sizes[1] / 2;
    const int* src = ei;
    const int* dst = ei + E;

    const float* w1[3]; const float* b1[3]; const float* gg[3];
    const float* be[3]; const float* w2[3]; const float* b2[3];
    for (int l = 0; l < 3; ++l) {
        w1[l] = (const float*)d_in[2 + 6 * l + 0];
        b1[l] = (const float*)d_in[2 + 6 * l + 1];
        gg[l] = (const float*)d_in[2 + 6 * l + 2];
        be[l] = (const float*)d_in[2 + 6 * l + 3];
        w2[l] = (const float*)d_in[2 + 6 * l + 4];
        b2[l] = (const float*)d_in[2 + 6 * l + 5];
    }

    // ---- workspace suballocation (64B aligned) ----
    char* ws = (char*)d_ws;
    size_t off = 0;
    auto alloc = [&](size_t bytes) {
        void* p = ws + off;
        off = align_up(off + bytes, 64);
        return p;
    };
    float* B0   = (float*)alloc((size_t)N * 128 * 4);
    float* B1   = (float*)alloc((size_t)N * 128 * 4);
    int* srcs   = (int*)alloc((size_t)E * 4);
    int* starts = (int*)alloc((size_t)(N + 1) * 4);
    int* cursor = (int*)alloc((size_t)N * 4);
    int* bsum   = (int*)alloc(256 * 4);
    float* sums = (float*)alloc(256 * 4);
    float* scsh = (float*)alloc(256 * 4);
    // weight hi/lo planes, transposed [DO][DI]
    const int wdims[6][2] = {{64,128},{128,128},{128,128},{128,128},{128,64},{64,64}};
    const float* wsrc[6] = {w1[0], w2[0], w1[1], w2[1], w1[2], w2[2]};
    short* wh[6]; short* wl[6];
    for (int i = 0; i < 6; ++i) {
        int elems = wdims[i][0] * wdims[i][1];
        wh[i] = (short*)alloc((size_t)elems * 2);
        wl[i] = (short*)alloc((size_t)elems * 2);
    }
    (void)ws_size; (void)n_in; (void)out_size;

    // ---- weight split (once per call) ----
    for (int i = 0; i < 6; ++i) {
        int elems = wdims[i][0] * wdims[i][1];
        wsplit_kernel<<<(elems + 255) / 256, 256, 0, stream>>>(
            wsrc[i], wh[i], wl[i], wdims[i][0], wdims[i][1]);
    }

    // ---- CSR build (once, reused by all 3 layers) ----
    hipMemsetAsync(cursor, 0, (size_t)N * 4, stream);
    hist_kernel<<<(E + 255) / 256, 256, 0, stream>>>(dst, cursor, E);
    int chunks = (N + 1023) / 1024;
    scan_part_kernel<<<chunks, 1024, 0, stream>>>(cursor, starts, bsum, N);
    scan_tops_kernel<<<1, 128, 0, stream>>>(bsum, chunks);
    scan_add_kernel<<<chunks, 1024, 0, stream>>>(starts, bsum, N, E);
    hipMemcpyAsync(cursor, starts, (size_t)N * 4, hipMemcpyDeviceToDevice, stream);
    fill_kernel<<<(E + 255) / 256, 256, 0, stream>>>(src, dst, cursor, srcs, E);

    const int nb = (N + 127) / 128;

    // ---- layer 0: 64 -> 128 -> 128 ----
    gather_kernel<64><<<N, 64, 0, stream>>>(x, starts, srcs, B0, N);
    gemm_mfma<64, 128, false><<<nb, 256, 0, stream>>>(
        B0, wh[0], wl[0], b1[0], nullptr, nullptr, B1, N);
    hipMemsetAsync(sums, 0, 2 * 128 * 4, stream);
    stats_kernel<128><<<512, 256, 0, stream>>>(B1, sums, N);
    bn_finalize_kernel<128><<<1, 128, 0, stream>>>(sums, gg[0], be[0], scsh, N);
    gemm_mfma<128, 128, true><<<nb, 256, 0, stream>>>(
        B1, wh[1], wl[1], b2[0], scsh, scsh + 128, B0, N);

    // ---- layer 1: 128 -> 128 -> 128 ----
    gather_kernel<128><<<N, 64, 0, stream>>>(B0, starts, srcs, B1, N);
    gemm_mfma<128, 128, false><<<nb, 256, 0, stream>>>(
        B1, wh[2], wl[2], b1[1], nullptr, nullptr, B0, N);
    hipMemsetAsync(sums, 0, 2 * 128 * 4, stream);
    stats_kernel<128><<<512, 256, 0, stream>>>(B0, sums, N);
    bn_finalize_kernel<128><<<1, 128, 0, stream>>>(sums, gg[1], be[1], scsh, N);
    gemm_mfma<128, 128, true><<<nb, 256, 0, stream>>>(
        B0, wh[3], wl[3], b2[1], scsh, scsh + 128, B1, N);

    // ---- layer 2: 128 -> 64 -> 64 ----
    gather_kernel<128><<<N, 64, 0, stream>>>(B1, starts, srcs, B0, N);
    gemm_mfma<128, 64, false><<<nb, 256, 0, stream>>>(
        B0, wh[4], wl[4], b1[2], nullptr, nullptr, B1, N);
    hipMemsetAsync(sums, 0, 2 * 64 * 4, stream);
    stats_kernel<64><<<512, 256, 0, stream>>>(B1, sums, N);
    bn_finalize_kernel<64><<<1, 64, 0, stream>>>(sums, gg[2], be[2], scsh, N);
    gemm_mfma<64, 64, true><<<nb, 256, 0, stream>>>(
        B1, wh[5], wl[5], b2[2], scsh, scsh + 64, (float*)d_out, N);
}